// Round 6
// baseline (17045.781 us; speedup 1.0000x reference)
//
#include <hip/hip_runtime.h>
#include <math.h>

#define NROWS 16384
#define KC 8192
#define DD 256
#define CAP 128
#define MARGIN 3.0e-4f

typedef __attribute__((ext_vector_type(8))) short bf16x8;
typedef __attribute__((ext_vector_type(4))) float f32x4;

__device__ __forceinline__ unsigned short f2bf(float f) {
    unsigned int u = __float_as_uint(f);
    unsigned int r = (u + 0x7FFFu + ((u >> 16) & 1u)) >> 16;   // RNE
    return (unsigned short)r;
}
__device__ __forceinline__ unsigned int fenc(float f) {        // monotone f32->u32
    unsigned int u = __float_as_uint(f);
    return (u & 0x80000000u) ? ~u : (u | 0x80000000u);
}
__device__ __forceinline__ float fdec(unsigned int u) {
    return __uint_as_float((u & 0x80000000u) ? (u & 0x7FFFFFFFu) : ~u);
}

// np-faithful exact rescore: d2 = fl(fl(A - 2*dot_chain) + C), dot = k-ascending
// single fma chain (matches BLAS sgemm accumulation; verified rounds 2-5).
// float4 loads, scalar chain order preserved (bit-identical).
__device__ __forceinline__ float exact_d2(const float* __restrict__ zrow,
                                          const float* __restrict__ crow,
                                          float A, float C)
{
    float dot = 0.0f;
#pragma unroll 8
    for (int d = 0; d < 64; ++d) {
        const float4 zv = *(const float4*)(zrow + 4 * d);
        const float4 cv = *(const float4*)(crow + 4 * d);
        dot = fmaf(zv.x, cv.x, dot);
        dot = fmaf(zv.y, cv.y, dot);
        dot = fmaf(zv.z, cv.z, dot);
        dot = fmaf(zv.w, cv.w, dot);
    }
    return __fadd_rn(__fsub_rn(A, 2.0f * dot), C);
}

// ---------------------------------------------------------------------------
// Prep: bf16 convert (all blocks) + np-pairwise norms (blocks < 1536) +
// cnt/rmin clears (blocks 1536..1663) + loss zero.  grid = 6144 x 256.
// ---------------------------------------------------------------------------
__global__ __launch_bounds__(256)
void vq_prep(const float* __restrict__ z, const float* __restrict__ cb,
             unsigned short* __restrict__ zb, unsigned short* __restrict__ cbb,
             float* __restrict__ cc, float* __restrict__ rowA,
             int* __restrict__ cnt, unsigned int* __restrict__ rmin,
             float* __restrict__ loss_ptr)
{
    const int t = threadIdx.x;
    const int b = blockIdx.x;
    const size_t i = (size_t)b * 256 + t;            // float4 index
    {
        const float* src; unsigned short* dst; size_t off;
        if (i < 1048576) { src = z;  dst = zb;  off = i; }
        else             { src = cb; dst = cbb; off = i - 1048576; }
        float4 v = *(const float4*)(src + off * 4);
        ushort4 o;
        o.x = f2bf(v.x); o.y = f2bf(v.y); o.z = f2bf(v.z); o.w = f2bf(v.w);
        *(ushort4*)(dst + off * 4) = o;
    }
    if (b < 1536) {   // norms: 24576 units, 16 lanes each (bit-faithful np.sum(x*x))
        const int unit = b * 16 + (t >> 4);
        const int l = t & 15;
        const float* p = (unit < KC) ? (cb + (size_t)unit * DD)
                                     : (z + (size_t)(unit - KC) * DD);
        const float* q = p + 128 * (l >> 3) + (l & 7);
        float x0 = q[0];
        float r = __fmul_rn(x0, x0);
#pragma unroll
        for (int k = 1; k < 16; ++k) {
            const float x = q[8 * k];
            r = __fadd_rn(r, __fmul_rn(x, x));
        }
        r = __fadd_rn(r, __shfl_xor(r, 1, 64));
        r = __fadd_rn(r, __shfl_xor(r, 2, 64));
        r = __fadd_rn(r, __shfl_xor(r, 4, 64));
        r = __fadd_rn(r, __shfl_xor(r, 8, 64));
        if (l == 0) {
            if (unit < KC) cc[unit] = r;
            else rowA[unit - KC] = r;
        }
    } else if (b < 1664) {   // clears
        const int u = (b - 1536) * 256 + t;
        if (u < NROWS) cnt[u] = 0;
        else rmin[u - NROWS] = 0xFFFFFFFFu;
    }
    if (i == 0) *loss_ptr = 0.0f;
}

// ---------------------------------------------------------------------------
// MFMA screen: 256 codes x 256 rows tile, BK=64 (4 chunks), double-buffered
// LDS with 2-phase pipeline (stage next chunk overlaps MFMA on current).
// 512 threads = 8 waves (4 code-slots x 2 row-slots), 4x8 register blocking.
// global_load_lds staging with inverse-swizzled source, swizzled ds_read_b128.
// disc = cc - 2*dot_bf16 reuses acc; per-row tile-min -> atomicMin rowmin;
// record candidates with disc <= rowmin_so_far + MARGIN.
// grid = (row_tiles=64 fast, code_tiles=32).
// ---------------------------------------------------------------------------
__global__ __launch_bounds__(512, 2)
void vq_gemm_screen(const unsigned short* __restrict__ cbb,
                    const unsigned short* __restrict__ zb,
                    const float* __restrict__ cc,
                    unsigned int* __restrict__ rowmin_u,
                    int* __restrict__ cnt, int* __restrict__ cand)
{
    __shared__ char Als[2][32768];        // codes  [256 rows][128 B], swizzled
    __shared__ char Bls[2][32768];        // z-rows [256 rows][128 B], swizzled
    __shared__ float ccs[256];
    __shared__ float colmin_lds[4][256];
    __shared__ float thr_lds[256];

    const int t = threadIdx.x;
    const int lane = t & 63;
    const int w = t >> 6;       // wave 0..7
    const int cw = w >> 1;      // code slot (64 codes each)
    const int rw = w & 1;       // row slot (128 rows each)
    const int gr = blockIdx.x;  // row tile (fast axis)
    const int gc = blockIdx.y;  // code tile

    const char* gA = (const char*)(cbb + (size_t)gc * 256 * DD);  // 512 B/row
    const char* gB = (const char*)(zb  + (size_t)gr * 256 * DD);

    if (t < 256) ccs[t] = cc[gc * 256 + t];

    f32x4 acc[4][8];
#pragma unroll
    for (int i = 0; i < 4; ++i)
#pragma unroll
        for (int j = 0; j < 8; ++j) acc[i][j] = (f32x4)0.0f;

    const int rA = lane & 15;
    const int kq = (lane >> 4) * 16;   // 16B k-slot within 64B K-step

    // stage one 64-elem K-chunk of both tiles into buffer bsel.
    // linear LDS dest (wave-uniform base + lane*16), inverse-swizzled source.
    auto STAGE = [&](int bsel, int kc) {
#pragma unroll
        for (int i = 0; i < 4; ++i) {
            const int o = (w * 4 + i) * 1024 + lane * 16;
            const int row = o >> 7;
            const int col = (o & 127) ^ ((row & 7) << 4);
            const int gofs = row * 512 + kc * 128 + col;
            __builtin_amdgcn_global_load_lds(
                (const unsigned int*)(gA + gofs),
                (unsigned int*)(Als[bsel] + (w * 4 + i) * 1024), 16, 0, 0);
            __builtin_amdgcn_global_load_lds(
                (const unsigned int*)(gB + gofs),
                (unsigned int*)(Bls[bsel] + (w * 4 + i) * 1024), 16, 0, 0);
        }
    };

    STAGE(0, 0);
    int cur = 0;
    for (int kc = 0; kc < 4; ++kc) {
        __syncthreads();               // buf[cur] staged (vmcnt0 + barrier)
        if (kc < 3) STAGE(cur ^ 1, kc + 1);   // overlap next stage w/ compute
#pragma unroll
        for (int ks = 0; ks < 2; ++ks) {
            bf16x8 af[4], bfr[8];
#pragma unroll
            for (int i = 0; i < 4; ++i) {
                const int c = cw * 64 + i * 16 + rA;
                af[i] = *(const bf16x8*)(Als[cur] + c * 128 +
                         ((ks * 64 + kq) ^ ((c & 7) << 4)));
            }
#pragma unroll
            for (int j = 0; j < 8; ++j) {
                const int r = rw * 128 + j * 16 + rA;
                bfr[j] = *(const bf16x8*)(Bls[cur] + r * 128 +
                          ((ks * 64 + kq) ^ ((r & 7) << 4)));
            }
#pragma unroll
            for (int i = 0; i < 4; ++i)
#pragma unroll
                for (int j = 0; j < 8; ++j)
                    acc[i][j] = __builtin_amdgcn_mfma_f32_16x16x32_bf16(
                        af[i], bfr[j], acc[i][j], 0, 0, 0);
        }
        cur ^= 1;
    }

    // ---- epilogue: disc into acc, per-z-row minima
    // C/D layout: col = lane&15 (z-row), row = (lane>>4)*4 + reg (code)
    const int lr = lane >> 4;
    float mj[8];
#pragma unroll
    for (int j = 0; j < 8; ++j) mj[j] = 3.0e38f;
#pragma unroll
    for (int i = 0; i < 4; ++i) {
#pragma unroll
        for (int r = 0; r < 4; ++r) {
            const float ccv = ccs[cw * 64 + i * 16 + lr * 4 + r];
#pragma unroll
            for (int j = 0; j < 8; ++j) {
                const float d = fmaf(-2.0f, acc[i][j][r], ccv);
                acc[i][j][r] = d;
                mj[j] = fminf(mj[j], d);
            }
        }
    }
#pragma unroll
    for (int j = 0; j < 8; ++j) {
        mj[j] = fminf(mj[j], __shfl_xor(mj[j], 16, 64));
        mj[j] = fminf(mj[j], __shfl_xor(mj[j], 32, 64));
        colmin_lds[cw][rw * 128 + j * 16 + rA] = mj[j];
    }
    __syncthreads();

    if (t < 256) {
        const float cm = fminf(fminf(colmin_lds[0][t], colmin_lds[1][t]),
                               fminf(colmin_lds[2][t], colmin_lds[3][t]));
        const unsigned int enc = fenc(cm);
        const unsigned int old = atomicMin(&rowmin_u[gr * 256 + t], enc);
        const unsigned int curm = (old < enc) ? old : enc;
        thr_lds[t] = fdec(curm) + MARGIN;
    }
    __syncthreads();

#pragma unroll
    for (int j = 0; j < 8; ++j) {
        const int colL = rw * 128 + j * 16 + rA;
        const float thr = thr_lds[colL];
        const int rowg = gr * 256 + colL;
#pragma unroll
        for (int i = 0; i < 4; ++i)
#pragma unroll
            for (int r = 0; r < 4; ++r)
                if (acc[i][j][r] <= thr) {
                    const int pos = atomicAdd(&cnt[rowg], 1);
                    if (pos < CAP)
                        cand[(size_t)rowg * CAP + pos] =
                            gc * 256 + cw * 64 + i * 16 + lr * 4 + r;
                }
    }
}

// ---------------------------------------------------------------------------
// Finalize + output fused. One wave per row: exact rescore of candidates
// (skip when n==1; exact full-scan whenever cnt is out of the valid range,
// so no path can produce an out-of-range gather index), then z_q/loss/idx.
// ---------------------------------------------------------------------------
__global__ __launch_bounds__(256)
void vq_finalize_out(const float* __restrict__ z, const float* __restrict__ cb,
                     const float* __restrict__ rowA, const float* __restrict__ cc,
                     const int* __restrict__ cnt, const int* __restrict__ cand,
                     float* __restrict__ zq, float* __restrict__ loss_ptr,
                     float* __restrict__ idx_out)
{
    __shared__ float wsum[4];
    const int t = threadIdx.x;
    const int lane = t & 63;
    const int w = t >> 6;
    const int row = blockIdx.x * 4 + w;
    const int n = cnt[row];
    const float* zrow = z + (size_t)row * DD;

    int bidx;
    if (n == 1) {
        bidx = cand[(size_t)row * CAP];    // margin guarantees this is argmin
        if ((unsigned)bidx >= (unsigned)KC) bidx = 0;   // defensive
    } else {
        const float A = rowA[row];
        float best = 3.0e38f;
        bidx = 0;
        bool first = true;
        if (n >= 1 && n <= CAP) {
            bidx = 0x7FFFFFFF;
            for (int base = 0; base < n; base += 64) {
                const int ci = base + lane;
                float d2 = 3.0e38f;
                int code = 0x7FFFFFFF;
                if (ci < n) {
                    code = cand[(size_t)row * CAP + ci];
                    if ((unsigned)code < (unsigned)KC)
                        d2 = exact_d2(zrow, cb + (size_t)code * DD, A, cc[code]);
                }
                if (d2 < best || (d2 == best && code < bidx)) { best = d2; bidx = code; }
            }
            first = (bidx == 0x7FFFFFFF);
        }
        if (n < 1 || n > CAP || first) {
            // exact full scan (correctness guarantee for any cnt state)
            best = 3.0e38f; bidx = 0x7FFFFFFF;
            for (int code = lane; code < KC; code += 64) {
                const float d2 = exact_d2(zrow, cb + (size_t)code * DD, A, cc[code]);
                if (d2 < best || (d2 == best && code < bidx)) { best = d2; bidx = code; }
            }
        }
#pragma unroll
        for (int m = 1; m < 64; m <<= 1) {
            const float ov = __shfl_xor(best, m, 64);
            const int oi = __shfl_xor(bidx, m, 64);
            if (ov < best || (ov == best && oi < bidx)) { best = ov; bidx = oi; }
        }
        if ((unsigned)bidx >= (unsigned)KC) bidx = 0;   // defensive
    }

    // ---- output phase (all lanes): z_q, loss, idx
    const int k = bidx;
    const float4 z4 = *(const float4*)(zrow + lane * 4);
    const float4 c4 = *(const float4*)(cb + (size_t)k * DD + lane * 4);
    float4 d4 = make_float4(c4.x - z4.x, c4.y - z4.y, c4.z - z4.z, c4.w - z4.w);
    float ss = fmaf(d4.x, d4.x, fmaf(d4.y, d4.y, fmaf(d4.z, d4.z, d4.w * d4.w)));
#pragma unroll
    for (int m = 1; m < 64; m <<= 1) ss += __shfl_xor(ss, m, 64);
    const float mag = sqrtf(ss);
    const float scale = mag / (mag + 1e-8f);
    float4 q = make_float4(fmaf(scale, d4.x, z4.x), fmaf(scale, d4.y, z4.y),
                           fmaf(scale, d4.z, z4.z), fmaf(scale, d4.w, z4.w));
    *(float4*)(zq + (size_t)row * DD + lane * 4) = q;
    if (lane == 0) {
        wsum[w] = ss;
        idx_out[row] = (float)k;
    }
    __syncthreads();
    if (t == 0) {
        const float s = (wsum[0] + wsum[1]) + (wsum[2] + wsum[3]);
        atomicAdd(loss_ptr, s * (1.25f / 4194304.0f));
    }
}

// ---------------------------------------------------------------------------
extern "C" void kernel_launch(void* const* d_in, const int* in_sizes, int n_in,
                              void* d_out, int out_size, void* d_ws, size_t ws_size,
                              hipStream_t stream)
{
    (void)in_sizes; (void)n_in; (void)out_size; (void)ws_size;
    const float* z = (const float*)d_in[0];
    const float* cb = (const float*)d_in[1];
    float* out = (float*)d_out;
    float* zq = out;                              // [0, 4194304)
    float* loss_ptr = out + (size_t)NROWS * DD;   // [4194304]
    float* idx_out = loss_ptr + 1;                // [4194305, +16384)

    char* ws = (char*)d_ws;
    unsigned short* zb   = (unsigned short*)(ws);                  //  8 MB
    unsigned short* cbb  = (unsigned short*)(ws + 8388608);        //  4 MB
    int*            cand = (int*)(ws + 12582912);                  //  8 MB
    int*            cnt  = (int*)(ws + 20971520);                  // 64 KB
    unsigned int*   rmin = (unsigned int*)(ws + 21037056);         // 64 KB
    float*          cc   = (float*)(ws + 21102592);                // 32 KB
    float*          rowA = (float*)(ws + 21135360);                // 64 KB

    vq_prep<<<6144, 256, 0, stream>>>(z, cb, zb, cbb, cc, rowA, cnt, rmin, loss_ptr);
    vq_gemm_screen<<<dim3(NROWS / 256, KC / 256), 512, 0, stream>>>(
        cbb, zb, cc, rmin, cnt, cand);
    vq_finalize_out<<<NROWS / 4, 256, 0, stream>>>(
        z, cb, rowA, cc, cnt, cand, zq, loss_ptr, idx_out);
}

// Round 7
// 275.221 us; speedup vs baseline: 61.9349x; 61.9349x over previous
//
#include <hip/hip_runtime.h>
#include <math.h>

#define NROWS 16384
#define KC 8192
#define DD 256
#define CAP 128
#define MARGIN 3.0e-4f

typedef __attribute__((ext_vector_type(8))) short bf16x8;
typedef __attribute__((ext_vector_type(4))) float f32x4;

__device__ __forceinline__ unsigned short f2bf(float f) {
    unsigned int u = __float_as_uint(f);
    unsigned int r = (u + 0x7FFFu + ((u >> 16) & 1u)) >> 16;   // RNE
    return (unsigned short)r;
}
__device__ __forceinline__ unsigned int fenc(float f) {        // monotone f32->u32
    unsigned int u = __float_as_uint(f);
    return (u & 0x80000000u) ? ~u : (u | 0x80000000u);
}
__device__ __forceinline__ float fdec(unsigned int u) {
    return __uint_as_float((u & 0x80000000u) ? (u & 0x7FFFFFFFu) : ~u);
}

// np-faithful exact rescore: d2 = fl(fl(A - 2*dot_chain) + C), dot = k-ascending
// single fma chain (matches BLAS sgemm accumulation; verified rounds 2-6).
// float4 loads, scalar chain order preserved (bit-identical).
__device__ __forceinline__ float exact_d2(const float* __restrict__ zrow,
                                          const float* __restrict__ crow,
                                          float A, float C)
{
    float dot = 0.0f;
#pragma unroll 8
    for (int d = 0; d < 64; ++d) {
        const float4 zv = *(const float4*)(zrow + 4 * d);
        const float4 cv = *(const float4*)(crow + 4 * d);
        dot = fmaf(zv.x, cv.x, dot);
        dot = fmaf(zv.y, cv.y, dot);
        dot = fmaf(zv.z, cv.z, dot);
        dot = fmaf(zv.w, cv.w, dot);
    }
    return __fadd_rn(__fsub_rn(A, 2.0f * dot), C);
}

// ---------------------------------------------------------------------------
// Prep: bf16 convert (all blocks) + np-pairwise norms (blocks < 1536) +
// cnt/rmin clears (blocks 1536..1663) + loss zero.  grid = 6144 x 256.
// ---------------------------------------------------------------------------
__global__ __launch_bounds__(256)
void vq_prep(const float* __restrict__ z, const float* __restrict__ cb,
             unsigned short* __restrict__ zb, unsigned short* __restrict__ cbb,
             float* __restrict__ cc, float* __restrict__ rowA,
             int* __restrict__ cnt, unsigned int* __restrict__ rmin,
             float* __restrict__ loss_ptr)
{
    const int t = threadIdx.x;
    const int b = blockIdx.x;
    const size_t i = (size_t)b * 256 + t;            // float4 index
    {
        const float* src; unsigned short* dst; size_t off;
        if (i < 1048576) { src = z;  dst = zb;  off = i; }
        else             { src = cb; dst = cbb; off = i - 1048576; }
        float4 v = *(const float4*)(src + off * 4);
        ushort4 o;
        o.x = f2bf(v.x); o.y = f2bf(v.y); o.z = f2bf(v.z); o.w = f2bf(v.w);
        *(ushort4*)(dst + off * 4) = o;
    }
    if (b < 1536) {   // norms: 24576 units, 16 lanes each (bit-faithful np.sum(x*x))
        const int unit = b * 16 + (t >> 4);
        const int l = t & 15;
        const float* p = (unit < KC) ? (cb + (size_t)unit * DD)
                                     : (z + (size_t)(unit - KC) * DD);
        const float* q = p + 128 * (l >> 3) + (l & 7);
        float x0 = q[0];
        float r = __fmul_rn(x0, x0);
#pragma unroll
        for (int k = 1; k < 16; ++k) {
            const float x = q[8 * k];
            r = __fadd_rn(r, __fmul_rn(x, x));
        }
        r = __fadd_rn(r, __shfl_xor(r, 1, 64));
        r = __fadd_rn(r, __shfl_xor(r, 2, 64));
        r = __fadd_rn(r, __shfl_xor(r, 4, 64));
        r = __fadd_rn(r, __shfl_xor(r, 8, 64));
        if (l == 0) {
            if (unit < KC) cc[unit] = r;
            else rowA[unit - KC] = r;
        }
    } else if (b < 1664) {   // clears
        const int u = (b - 1536) * 256 + t;
        if (u < NROWS) cnt[u] = 0;
        else rmin[u - NROWS] = 0xFFFFFFFFu;
    }
    if (i == 0) *loss_ptr = 0.0f;
}

// ---------------------------------------------------------------------------
// MFMA screen: 256 codes x 256 rows tile, BK=64 (4 chunks), double-buffered
// LDS with 2-phase pipeline (stage next chunk overlaps MFMA on current).
// 512 threads = 8 waves (4 code-slots x 2 row-slots), 4x8 register blocking.
// global_load_lds staging with inverse-swizzled source, swizzled ds_read_b128.
// disc = cc - 2*dot_bf16 reuses acc; per-row tile-min -> atomicMin rowmin;
// record candidates with disc <= rowmin_so_far + MARGIN.
// grid = (row_tiles=64 fast, code_tiles=32).  (unchanged from round 6)
// ---------------------------------------------------------------------------
__global__ __launch_bounds__(512, 2)
void vq_gemm_screen(const unsigned short* __restrict__ cbb,
                    const unsigned short* __restrict__ zb,
                    const float* __restrict__ cc,
                    unsigned int* __restrict__ rowmin_u,
                    int* __restrict__ cnt, int* __restrict__ cand)
{
    __shared__ char Als[2][32768];        // codes  [256 rows][128 B], swizzled
    __shared__ char Bls[2][32768];        // z-rows [256 rows][128 B], swizzled
    __shared__ float ccs[256];
    __shared__ float colmin_lds[4][256];
    __shared__ float thr_lds[256];

    const int t = threadIdx.x;
    const int lane = t & 63;
    const int w = t >> 6;       // wave 0..7
    const int cw = w >> 1;      // code slot (64 codes each)
    const int rw = w & 1;       // row slot (128 rows each)
    const int gr = blockIdx.x;  // row tile (fast axis)
    const int gc = blockIdx.y;  // code tile

    const char* gA = (const char*)(cbb + (size_t)gc * 256 * DD);  // 512 B/row
    const char* gB = (const char*)(zb  + (size_t)gr * 256 * DD);

    if (t < 256) ccs[t] = cc[gc * 256 + t];

    f32x4 acc[4][8];
#pragma unroll
    for (int i = 0; i < 4; ++i)
#pragma unroll
        for (int j = 0; j < 8; ++j) acc[i][j] = (f32x4)0.0f;

    const int rA = lane & 15;
    const int kq = (lane >> 4) * 16;   // 16B k-slot within 64B K-step

    // stage one 64-elem K-chunk of both tiles into buffer bsel.
    // linear LDS dest (wave-uniform base + lane*16), inverse-swizzled source.
    auto STAGE = [&](int bsel, int kc) {
#pragma unroll
        for (int i = 0; i < 4; ++i) {
            const int o = (w * 4 + i) * 1024 + lane * 16;
            const int row = o >> 7;
            const int col = (o & 127) ^ ((row & 7) << 4);
            const int gofs = row * 512 + kc * 128 + col;
            __builtin_amdgcn_global_load_lds(
                (const unsigned int*)(gA + gofs),
                (unsigned int*)(Als[bsel] + (w * 4 + i) * 1024), 16, 0, 0);
            __builtin_amdgcn_global_load_lds(
                (const unsigned int*)(gB + gofs),
                (unsigned int*)(Bls[bsel] + (w * 4 + i) * 1024), 16, 0, 0);
        }
    };

    STAGE(0, 0);
    int cur = 0;
    for (int kc = 0; kc < 4; ++kc) {
        __syncthreads();               // buf[cur] staged (vmcnt0 + barrier)
        if (kc < 3) STAGE(cur ^ 1, kc + 1);   // overlap next stage w/ compute
#pragma unroll
        for (int ks = 0; ks < 2; ++ks) {
            bf16x8 af[4], bfr[8];
#pragma unroll
            for (int i = 0; i < 4; ++i) {
                const int c = cw * 64 + i * 16 + rA;
                af[i] = *(const bf16x8*)(Als[cur] + c * 128 +
                         ((ks * 64 + kq) ^ ((c & 7) << 4)));
            }
#pragma unroll
            for (int j = 0; j < 8; ++j) {
                const int r = rw * 128 + j * 16 + rA;
                bfr[j] = *(const bf16x8*)(Bls[cur] + r * 128 +
                          ((ks * 64 + kq) ^ ((r & 7) << 4)));
            }
#pragma unroll
            for (int i = 0; i < 4; ++i)
#pragma unroll
                for (int j = 0; j < 8; ++j)
                    acc[i][j] = __builtin_amdgcn_mfma_f32_16x16x32_bf16(
                        af[i], bfr[j], acc[i][j], 0, 0, 0);
        }
        cur ^= 1;
    }

    // ---- epilogue: disc into acc, per-z-row minima
    // C/D layout: col = lane&15 (z-row), row = (lane>>4)*4 + reg (code)
    const int lr = lane >> 4;
    float mj[8];
#pragma unroll
    for (int j = 0; j < 8; ++j) mj[j] = 3.0e38f;
#pragma unroll
    for (int i = 0; i < 4; ++i) {
#pragma unroll
        for (int r = 0; r < 4; ++r) {
            const float ccv = ccs[cw * 64 + i * 16 + lr * 4 + r];
#pragma unroll
            for (int j = 0; j < 8; ++j) {
                const float d = fmaf(-2.0f, acc[i][j][r], ccv);
                acc[i][j][r] = d;
                mj[j] = fminf(mj[j], d);
            }
        }
    }
#pragma unroll
    for (int j = 0; j < 8; ++j) {
        mj[j] = fminf(mj[j], __shfl_xor(mj[j], 16, 64));
        mj[j] = fminf(mj[j], __shfl_xor(mj[j], 32, 64));
        colmin_lds[cw][rw * 128 + j * 16 + rA] = mj[j];
    }
    __syncthreads();

    if (t < 256) {
        const float cm = fminf(fminf(colmin_lds[0][t], colmin_lds[1][t]),
                               fminf(colmin_lds[2][t], colmin_lds[3][t]));
        const unsigned int enc = fenc(cm);
        const unsigned int old = atomicMin(&rowmin_u[gr * 256 + t], enc);
        const unsigned int curm = (old < enc) ? old : enc;
        thr_lds[t] = fdec(curm) + MARGIN;
    }
    __syncthreads();

#pragma unroll
    for (int j = 0; j < 8; ++j) {
        const int colL = rw * 128 + j * 16 + rA;
        const float thr = thr_lds[colL];
        const int rowg = gr * 256 + colL;
#pragma unroll
        for (int i = 0; i < 4; ++i)
#pragma unroll
            for (int r = 0; r < 4; ++r)
                if (acc[i][j][r] <= thr) {
                    const int pos = atomicAdd(&cnt[rowg], 1);
                    if (pos < CAP)
                        cand[(size_t)rowg * CAP + pos] =
                            gc * 256 + cw * 64 + i * 16 + lr * 4 + r;
                }
    }
}

// ---------------------------------------------------------------------------
// Finalize + output fused. One wave per row: exact rescore of candidates.
// The full-scan fallback decision is WAVE-UNIFORM: it is taken only from the
// post-reduction result (or an out-of-range cnt), never from per-lane state.
// ---------------------------------------------------------------------------
__global__ __launch_bounds__(256)
void vq_finalize_out(const float* __restrict__ z, const float* __restrict__ cb,
                     const float* __restrict__ rowA, const float* __restrict__ cc,
                     const int* __restrict__ cnt, const int* __restrict__ cand,
                     float* __restrict__ zq, float* __restrict__ loss_ptr,
                     float* __restrict__ idx_out)
{
    __shared__ float wsum[4];
    const int t = threadIdx.x;
    const int lane = t & 63;
    const int w = t >> 6;
    const int row = blockIdx.x * 4 + w;
    const int n = cnt[row];
    const float A = rowA[row];
    const float* zrow = z + (size_t)row * DD;

    int bidx = 0x7FFFFFFF;
    bool need_full = (n < 1 || n > CAP);     // uniform: same n for whole wave
    if (!need_full) {
        if (n == 1) {
            bidx = cand[(size_t)row * CAP];
            if ((unsigned)bidx >= (unsigned)KC) need_full = true;
        } else {
            float best = 3.0e38f;
            for (int base = 0; base < n; base += 64) {
                const int ci = base + lane;
                float d2 = 3.0e38f;
                int code = 0x7FFFFFFF;
                if (ci < n) {
                    code = cand[(size_t)row * CAP + ci];
                    if ((unsigned)code < (unsigned)KC)
                        d2 = exact_d2(zrow, cb + (size_t)code * DD, A, cc[code]);
                    else
                        code = 0x7FFFFFFF;
                }
                if (d2 < best || (d2 == best && code < bidx)) { best = d2; bidx = code; }
            }
#pragma unroll
            for (int m = 1; m < 64; m <<= 1) {
                const float ov = __shfl_xor(best, m, 64);
                const int oi = __shfl_xor(bidx, m, 64);
                if (ov < best || (ov == best && oi < bidx)) { best = ov; bidx = oi; }
            }
            // post-reduction: all lanes hold the same winner -> uniform check
            if ((unsigned)bidx >= (unsigned)KC) need_full = true;
        }
    }
    if (need_full) {
        // exact full scan (correctness guarantee for any cnt/cand state)
        float best = 3.0e38f;
        bidx = 0x7FFFFFFF;
        for (int code = lane; code < KC; code += 64) {
            const float d2 = exact_d2(zrow, cb + (size_t)code * DD, A, cc[code]);
            if (d2 < best || (d2 == best && code < bidx)) { best = d2; bidx = code; }
        }
#pragma unroll
        for (int m = 1; m < 64; m <<= 1) {
            const float ov = __shfl_xor(best, m, 64);
            const int oi = __shfl_xor(bidx, m, 64);
            if (ov < best || (ov == best && oi < bidx)) { best = ov; bidx = oi; }
        }
        if ((unsigned)bidx >= (unsigned)KC) bidx = 0;   // defensive
    }

    // ---- output phase (all lanes): z_q, loss, idx
    const int k = bidx;
    const float4 z4 = *(const float4*)(zrow + lane * 4);
    const float4 c4 = *(const float4*)(cb + (size_t)k * DD + lane * 4);
    float4 d4 = make_float4(c4.x - z4.x, c4.y - z4.y, c4.z - z4.z, c4.w - z4.w);
    float ss = fmaf(d4.x, d4.x, fmaf(d4.y, d4.y, fmaf(d4.z, d4.z, d4.w * d4.w)));
#pragma unroll
    for (int m = 1; m < 64; m <<= 1) ss += __shfl_xor(ss, m, 64);
    const float mag = sqrtf(ss);
    const float scale = mag / (mag + 1e-8f);
    float4 q = make_float4(fmaf(scale, d4.x, z4.x), fmaf(scale, d4.y, z4.y),
                           fmaf(scale, d4.z, z4.z), fmaf(scale, d4.w, z4.w));
    *(float4*)(zq + (size_t)row * DD + lane * 4) = q;
    if (lane == 0) {
        wsum[w] = ss;
        idx_out[row] = (float)k;
    }
    __syncthreads();
    if (t == 0) {
        const float s = (wsum[0] + wsum[1]) + (wsum[2] + wsum[3]);
        atomicAdd(loss_ptr, s * (1.25f / 4194304.0f));
    }
}

// ---------------------------------------------------------------------------
extern "C" void kernel_launch(void* const* d_in, const int* in_sizes, int n_in,
                              void* d_out, int out_size, void* d_ws, size_t ws_size,
                              hipStream_t stream)
{
    (void)in_sizes; (void)n_in; (void)out_size; (void)ws_size;
    const float* z = (const float*)d_in[0];
    const float* cb = (const float*)d_in[1];
    float* out = (float*)d_out;
    float* zq = out;                              // [0, 4194304)
    float* loss_ptr = out + (size_t)NROWS * DD;   // [4194304]
    float* idx_out = loss_ptr + 1;                // [4194305, +16384)

    char* ws = (char*)d_ws;
    unsigned short* zb   = (unsigned short*)(ws);                  //  8 MB
    unsigned short* cbb  = (unsigned short*)(ws + 8388608);        //  4 MB
    int*            cand = (int*)(ws + 12582912);                  //  8 MB
    int*            cnt  = (int*)(ws + 20971520);                  // 64 KB
    unsigned int*   rmin = (unsigned int*)(ws + 21037056);         // 64 KB
    float*          cc   = (float*)(ws + 21102592);                // 32 KB
    float*          rowA = (float*)(ws + 21135360);                // 64 KB

    vq_prep<<<6144, 256, 0, stream>>>(z, cb, zb, cbb, cc, rowA, cnt, rmin, loss_ptr);
    vq_gemm_screen<<<dim3(NROWS / 256, KC / 256), 512, 0, stream>>>(
        cbb, zb, cc, rmin, cnt, cand);
    vq_finalize_out<<<NROWS / 4, 256, 0, stream>>>(
        z, cb, rowA, cc, cnt, cand, zq, loss_ptr, idx_out);
}